// Round 9
// baseline (7972.182 us; speedup 1.0000x reference)
//
#include <hip/hip_runtime.h>

#define BLOCK 256
#define DDIM 64
#define SCAN_CHUNK 2048   // tier-2 scan: 256 threads * 8 elements
#define NBMAX 128         // tier-2 max scan chunks per segment
#define NBB 512           // tier-1 bucket array stride (buckets per segment <= 512)
#define BSHIFT 9          // 512 rows per bucket (fits 512*64 fp32 = 128 KB LDS)
#define TILE 16384        // tier-1 edges per partition tile
#define TITER (TILE / 256)
#define GRAN_SHIFT 11     // src sort granularity: 2048 rows
#define NGRAN 128         // max granules: 2^18 >> 11
#define SORT_CAP 14336    // max edges per bucket for LDS sort (112 KB)

// ---------- elementwise / small kernels ----------

__global__ void first_comb4(float4* __restrict__ dst, const float4* __restrict__ emb0,
                            const float* __restrict__ scale, long n4) {
    long idx = blockIdx.x * (long)blockDim.x + threadIdx.x;
    long stride = (long)gridDim.x * blockDim.x;
    for (; idx < n4; idx += stride) {
        float s = 1.0f + scale[idx >> 4];
        float4 e = emb0[idx];
        e.x *= s; e.y *= s; e.z *= s; e.w *= s;
        dst[idx] = e;
    }
}

__global__ void add_scaled4(float4* __restrict__ cur, const float4* __restrict__ emb0,
                            const float* __restrict__ scale, long n4) {
    long idx = blockIdx.x * (long)blockDim.x + threadIdx.x;
    long stride = (long)gridDim.x * blockDim.x;
    for (; idx < n4; idx += stride) {
        float s = scale[idx >> 4];
        float4 e = emb0[idx];
        float4 c = cur[idx];
        c.x += s * e.x; c.y += s * e.y; c.z += s * e.z; c.w += s * e.w;
        cur[idx] = c;
    }
}

__global__ void gather_add(float* __restrict__ acc, const float* __restrict__ emb,
                           const int* __restrict__ idxs, int batch) {
    int t = blockIdx.x * blockDim.x + threadIdx.x;
    if (t >= batch * DDIM) return;
    int b = t >> 6;
    acc[t] += emb[(long)idxs[b] * DDIM + (t & 63)];
}

__global__ void gather_add_corr(float* __restrict__ acc, const float* __restrict__ aug,
                                const float* __restrict__ scale, const float* __restrict__ emb0,
                                const int* __restrict__ idxs, int batch) {
    int t = blockIdx.x * blockDim.x + threadIdx.x;
    if (t >= batch * DDIM) return;
    int b = t >> 6;
    long r = idxs[b];
    long o = r * DDIM + (t & 63);
    acc[t] += aug[o] - scale[r] * emb0[o];
}

__global__ void final_gamma(const float* __restrict__ uacc, const float* __restrict__ iacc,
                            float* __restrict__ out, int batch) {
    int t = blockIdx.x * blockDim.x + threadIdx.x;
    if (t >= batch * DDIM) return;
    int b = t >> 6;
    float v = uacc[t] * iacc[t];
    #pragma unroll
    for (int off = 32; off; off >>= 1) v += __shfl_down(v, off, 64);
    if ((threadIdx.x & 63) == 0) out[b] = v * (1.0f / 16.0f);
}

// ---------- tier-1 build: bucket partition + within-bucket src sort ----------

struct Seg {
    const int*   keys;   // dst index (bucketed)
    const int*   other;  // src index
    const float* vals;
    int n;
    int tiles;
    long stg_off;
};

// P0: count edges per (segment, bucket)
__global__ void bucket_count(Seg s0, Seg s1, Seg s2, Seg s3, int* __restrict__ gcnt) {
    __shared__ int h[NBB];
    int b = blockIdx.x; Seg s; int seg;
    if (b < s0.tiles)                              { s = s0; seg = 0; }
    else if (b < s0.tiles + s1.tiles)              { s = s1; seg = 1; b -= s0.tiles; }
    else if (b < s0.tiles + s1.tiles + s2.tiles)   { s = s2; seg = 2; b -= s0.tiles + s1.tiles; }
    else                                           { s = s3; seg = 3; b -= s0.tiles + s1.tiles + s2.tiles; }
    int tid = threadIdx.x;
    for (int i = tid; i < NBB; i += blockDim.x) h[i] = 0;
    __syncthreads();
    int base = b * TILE;
    for (int k = 0; k < TITER; ++k) {
        int i = base + k * 256 + tid;
        if (i < s.n) atomicAdd(&h[s.keys[i] >> BSHIFT], 1);
    }
    __syncthreads();
    for (int i = tid; i < NBB; i += blockDim.x)
        if (h[i]) atomicAdd(&gcnt[seg * NBB + i], h[i]);
}

// P0s: per-segment exclusive scan (512 wide)
__global__ void bucket_scan512(const int* __restrict__ gcnt, int* __restrict__ gbase,
                               int* __restrict__ grun,
                               int nb0, int nb1, int nb2, int nb3) {
    __shared__ int sd[NBB];
    int seg = blockIdx.x;
    int nb = seg == 0 ? nb0 : seg == 1 ? nb1 : seg == 2 ? nb2 : nb3;
    int t = threadIdx.x;
    int v = (t < nb) ? gcnt[seg * NBB + t] : 0;
    sd[t] = v;
    __syncthreads();
    for (int off = 1; off < NBB; off <<= 1) {
        int a = (t >= off) ? sd[t - off] : 0;
        __syncthreads();
        sd[t] += a;
        __syncthreads();
    }
    if (t < nb) { gbase[seg * NBB + t] = sd[t] - v; grun[seg * NBB + t] = sd[t] - v; }
}

// P1: partition edges into bucket-contiguous staging, packed (dst_local<<18)|src
__global__ void bucket_part(Seg s0, Seg s1, Seg s2, Seg s3,
                            int* __restrict__ grun, int2* __restrict__ stg) {
    __shared__ int h[NBB];
    __shared__ int hb[NBB];
    int b = blockIdx.x; Seg s; int seg;
    if (b < s0.tiles)                              { s = s0; seg = 0; }
    else if (b < s0.tiles + s1.tiles)              { s = s1; seg = 1; b -= s0.tiles; }
    else if (b < s0.tiles + s1.tiles + s2.tiles)   { s = s2; seg = 2; b -= s0.tiles + s1.tiles; }
    else                                           { s = s3; seg = 3; b -= s0.tiles + s1.tiles + s2.tiles; }
    int tid = threadIdx.x;
    for (int i = tid; i < NBB; i += blockDim.x) h[i] = 0;
    __syncthreads();
    int base = b * TILE;
    for (int k = 0; k < TITER; ++k) {
        int i = base + k * 256 + tid;
        if (i < s.n) atomicAdd(&h[s.keys[i] >> BSHIFT], 1);
    }
    __syncthreads();
    for (int i = tid; i < NBB; i += blockDim.x) {
        int c = h[i];
        if (c) hb[i] = atomicAdd(&grun[seg * NBB + i], c);
        h[i] = 0;   // becomes within-chunk cursor
    }
    __syncthreads();
    int2* out = stg + s.stg_off;
    for (int k = 0; k < TITER; ++k) {
        int i = base + k * 256 + tid;
        if (i < s.n) {
            int key = s.keys[i];
            int bk = key >> BSHIFT;
            int rl = key & ((1 << BSHIFT) - 1);
            int slot = atomicAdd(&h[bk], 1);
            out[hb[bk] + slot] = make_int2((rl << 18) | s.other[i], __float_as_int(s.vals[i]));
        }
    }
}

struct SegS {
    long stg_off;
    int2* out;
    int nb;
};

// P2: per-bucket sort by src granule (LDS counting sort); fallback: plain copy
__global__ void bucket_sortsrc(SegS s0, SegS s1, SegS s2, SegS s3,
                               const int* __restrict__ gbase, const int* __restrict__ gcnt,
                               const int2* __restrict__ stg) {
    extern __shared__ int2 lbuf[];
    __shared__ int curs[NGRAN];
    int b = blockIdx.x; SegS s; int seg;
    if (b < s0.nb)                     { s = s0; seg = 0; }
    else if (b < s0.nb + s1.nb)        { s = s1; seg = 1; b -= s0.nb; }
    else if (b < s0.nb + s1.nb + s2.nb){ s = s2; seg = 2; b -= s0.nb + s1.nb; }
    else                               { s = s3; seg = 3; b -= s0.nb + s1.nb + s2.nb; }
    int tid = threadIdx.x;
    int start = gbase[seg * NBB + b];
    int cnt = gcnt[seg * NBB + b];
    const int2* in = stg + s.stg_off + start;
    int2* out = s.out + start;

    if (cnt > SORT_CAP) {   // rare fallback: copy unsorted (correct, less locality)
        for (int i = tid; i < cnt; i += blockDim.x) out[i] = in[i];
        return;
    }
    for (int i = tid; i < NGRAN; i += blockDim.x) curs[i] = 0;
    __syncthreads();
    for (int i = tid; i < cnt; i += blockDim.x) {
        int2 e = in[i];
        lbuf[i] = e;
        atomicAdd(&curs[(e.x & 0x3FFFF) >> GRAN_SHIFT], 1);
    }
    __syncthreads();
    if (tid == 0) {
        int run = 0;
        for (int g = 0; g < NGRAN; ++g) { int c = curs[g]; curs[g] = run; run += c; }
    }
    __syncthreads();
    for (int i = tid; i < cnt; i += blockDim.x) {
        int2 e = lbuf[i];
        int g = (e.x & 0x3FFFF) >> GRAN_SHIFT;
        int pos = atomicAdd(&curs[g], 1);
        out[pos] = e;
    }
}

// ---------- tier-1 pull: src-major edge stream into LDS-resident dst bucket ----------

__device__ __forceinline__ void lds_seg(float* acc, const int2* __restrict__ e, int cnt,
                                        const float* __restrict__ x, int lane, int w, int nw) {
    for (int bi = w * 8; bi < cnt; bi += nw * 8) {
        int2 ed[8];
        #pragma unroll
        for (int k = 0; k < 8; ++k)
            ed[k] = (bi + k < cnt) ? e[bi + k] : make_int2(0, 0);
        float xv[8];
        #pragma unroll
        for (int k = 0; k < 8; ++k)
            xv[k] = x[(long)(ed[k].x & 0x3FFFF) * DDIM + lane];
        #pragma unroll
        for (int k = 0; k < 8; ++k) {
            float v = __int_as_float(ed[k].y);
            atomicAdd(&acc[((unsigned)ed[k].x >> 18) * DDIM + lane], v * xv[k]);
        }
    }
}

__global__ __launch_bounds__(1024) void spmm_lds_full(
    const int2* __restrict__ eA, const int* __restrict__ gbA, const int* __restrict__ gcA,
    const float* __restrict__ xA,
    const int2* __restrict__ eB, const int* __restrict__ gbB, const int* __restrict__ gcB,
    const float* __restrict__ xB,
    float* __restrict__ out_raw, float* __restrict__ out_aug,
    const float* __restrict__ scale, const float* __restrict__ emb0, int R) {
    extern __shared__ float acc[];   // 512*64 floats = 128 KB
    int tid = threadIdx.x;
    int b = blockIdx.x;
    float4 z4 = make_float4(0.f, 0.f, 0.f, 0.f);
    for (int i = tid; i < (512 * DDIM) / 4; i += blockDim.x) ((float4*)acc)[i] = z4;
    __syncthreads();
    int lane = tid & 63, w = tid >> 6, nw = blockDim.x >> 6;
    lds_seg(acc, eA + gbA[b], gcA[b], xA, lane, w, nw);
    lds_seg(acc, eB + gbB[b], gcB[b], xB, lane, w, nw);
    __syncthreads();
    int lo = b << BSHIFT;
    int nloc = R - lo; if (nloc > 512) nloc = 512;
    for (int i = tid; i < nloc * 16; i += blockDim.x) {
        int row = i >> 4;
        long go = (long)(lo + row) * 16 + (i & 15);
        float4 a = ((float4*)acc)[row * 16 + (i & 15)];
        if (out_raw) ((float4*)out_raw)[go] = a;
        if (out_aug) {
            float s = scale[lo + row];
            float4 e0 = ((const float4*)emb0)[go];
            a.x += s * e0.x; a.y += s * e0.y; a.z += s * e0.z; a.w += s * e0.w;
            ((float4*)out_aug)[go] = a;
        }
    }
}

// same compute; epilogue accumulates only sampled rows into racc[b,:]
__global__ __launch_bounds__(1024) void spmm_lds_rows(
    const int2* __restrict__ eA, const int* __restrict__ gbA, const int* __restrict__ gcA,
    const float* __restrict__ xA,
    const int2* __restrict__ eB, const int* __restrict__ gbB, const int* __restrict__ gcB,
    const float* __restrict__ xB,
    const int* __restrict__ rowlist, float* __restrict__ racc, int batch) {
    extern __shared__ float acc[];
    int tid = threadIdx.x;
    int b = blockIdx.x;
    float4 z4 = make_float4(0.f, 0.f, 0.f, 0.f);
    for (int i = tid; i < (512 * DDIM) / 4; i += blockDim.x) ((float4*)acc)[i] = z4;
    __syncthreads();
    int lane = tid & 63, w = tid >> 6, nw = blockDim.x >> 6;
    lds_seg(acc, eA + gbA[b], gcA[b], xA, lane, w, nw);
    lds_seg(acc, eB + gbB[b], gcB[b], xB, lane, w, nw);
    __syncthreads();
    for (int bi = w; bi < batch; bi += nw) {
        int row = rowlist[bi];
        if ((row >> BSHIFT) == b)
            racc[(long)bi * DDIM + lane] += acc[(row & 511) * DDIM + lane];
    }
}

// ---------- tier-2: CSR row-pull path (round-8 proven) ----------

__device__ __forceinline__ void row_part_csr(const int* __restrict__ rp,
                                             const int2* __restrict__ ee,
                                             const float* __restrict__ x,
                                             int row, int lane,
                                             float4& acc0, float4& acc1) {
    const int l16 = lane & 15;
    const int g = lane >> 4;
    const float4* x4 = (const float4*)x;
    int s = rp[row], e = rp[row + 1];
    for (int j = s; j < e; j += 64) {
        int cnt = e - j; if (cnt > 64) cnt = 64;
        int myc = 0; float myv = 0.0f;
        if (lane < cnt) { int2 pr = ee[j + lane]; myc = pr.x; myv = __int_as_float(pr.y); }
        int steps = (cnt + 7) >> 3;
        #pragma unroll 2
        for (int st = 0; st < steps; ++st) {
            int t0 = st * 8 + g;
            int t1 = t0 + 4;
            int c0 = __shfl(myc, t0, 64); float w0 = __shfl(myv, t0, 64);
            int c1 = __shfl(myc, t1, 64); float w1 = __shfl(myv, t1, 64);
            bool ok0 = t0 < cnt, ok1 = t1 < cnt;
            c0 = ok0 ? c0 : 0; w0 = ok0 ? w0 : 0.0f;
            c1 = ok1 ? c1 : 0; w1 = ok1 ? w1 : 0.0f;
            float4 xv0 = x4[(long)c0 * 16 + l16];
            float4 xv1 = x4[(long)c1 * 16 + l16];
            acc0.x += w0 * xv0.x; acc0.y += w0 * xv0.y; acc0.z += w0 * xv0.z; acc0.w += w0 * xv0.w;
            acc1.x += w1 * xv1.x; acc1.y += w1 * xv1.y; acc1.z += w1 * xv1.z; acc1.w += w1 * xv1.w;
        }
    }
}

__device__ __forceinline__ float4 group_reduce(float4 a) {
    a.x += __shfl_xor(a.x, 16, 64); a.y += __shfl_xor(a.y, 16, 64);
    a.z += __shfl_xor(a.z, 16, 64); a.w += __shfl_xor(a.w, 16, 64);
    a.x += __shfl_xor(a.x, 32, 64); a.y += __shfl_xor(a.y, 32, 64);
    a.z += __shfl_xor(a.z, 32, 64); a.w += __shfl_xor(a.w, 32, 64);
    return a;
}

__global__ void pull2csr(const int* __restrict__ rpA, const int2* __restrict__ eA, const float* __restrict__ xA,
                         const int* __restrict__ rpB, const int2* __restrict__ eB, const float* __restrict__ xB,
                         float* __restrict__ out_raw, float* __restrict__ out_aug,
                         const float* __restrict__ scale, const float* __restrict__ emb0,
                         int nrows) {
    int wave = (int)((blockIdx.x * (long)blockDim.x + threadIdx.x) >> 6);
    int lane = threadIdx.x & 63;
    if (wave >= nrows) return;
    float4 z = make_float4(0.f, 0.f, 0.f, 0.f);
    float4 a0 = z, a1 = z;
    row_part_csr(rpA, eA, xA, wave, lane, a0, a1);
    row_part_csr(rpB, eB, xB, wave, lane, a0, a1);
    a0.x += a1.x; a0.y += a1.y; a0.z += a1.z; a0.w += a1.w;
    a0 = group_reduce(a0);
    if (lane < 16) {
        long o = (long)wave * 16 + lane;
        if (out_raw) ((float4*)out_raw)[o] = a0;
        if (out_aug) {
            float s = scale[wave];
            float4 e0 = ((const float4*)emb0)[o];
            float4 g = a0;
            g.x += s * e0.x; g.y += s * e0.y; g.z += s * e0.z; g.w += s * e0.w;
            ((float4*)out_aug)[o] = g;
        }
    }
}

__global__ void pull2csr_rows(const int* __restrict__ rpA, const int2* __restrict__ eA, const float* __restrict__ xA,
                              const int* __restrict__ rpB, const int2* __restrict__ eB, const float* __restrict__ xB,
                              const int* __restrict__ rowlist, float* __restrict__ acc, int nlist) {
    int w = (int)((blockIdx.x * (long)blockDim.x + threadIdx.x) >> 6);
    int lane = threadIdx.x & 63;
    if (w >= nlist) return;
    int row = rowlist[w];
    float4 z = make_float4(0.f, 0.f, 0.f, 0.f);
    float4 a0 = z, a1 = z;
    row_part_csr(rpA, eA, xA, row, lane, a0, a1);
    row_part_csr(rpB, eB, xB, row, lane, a0, a1);
    a0.x += a1.x; a0.y += a1.y; a0.z += a1.z; a0.w += a1.w;
    a0 = group_reduce(a0);
    if (lane < 16) {
        float4* acc4 = (float4*)acc;
        float4 cur = acc4[(long)w * 16 + lane];
        cur.x += a0.x; cur.y += a0.y; cur.z += a0.z; cur.w += a0.w;
        acc4[(long)w * 16 + lane] = cur;
    }
}

__global__ void hist4(const int* __restrict__ a0, long n0, int* __restrict__ c0,
                      const int* __restrict__ a1, long n1, int* __restrict__ c1,
                      const int* __restrict__ a2, long n2, int* __restrict__ c2,
                      const int* __restrict__ a3, long n3, int* __restrict__ c3) {
    long idx = blockIdx.x * (long)blockDim.x + threadIdx.x;
    long stride = (long)gridDim.x * blockDim.x;
    long t01 = n0 + n1, t012 = n0 + n1 + n2, total = t012 + n3;
    for (; idx < total; idx += stride) {
        if (idx < n0)        atomicAdd(&c0[a0[idx]], 1);
        else if (idx < t01)  atomicAdd(&c1[a1[idx - n0]], 1);
        else if (idx < t012) atomicAdd(&c2[a2[idx - t01]], 1);
        else                 atomicAdd(&c3[a3[idx - t012]], 1);
    }
}

__global__ void block_sums4(const int* __restrict__ i0, int n0, int nb0,
                            const int* __restrict__ i1, int n1, int nb1,
                            const int* __restrict__ i2, int n2, int nb2,
                            const int* __restrict__ i3, int n3, int nb3,
                            int* __restrict__ bsum) {
    __shared__ int sdata[256];
    int b = blockIdx.x, seg, lb; const int* in; int n;
    if (b < nb0)                 { seg = 0; lb = b;                 in = i0; n = n0; }
    else if (b < nb0 + nb1)      { seg = 1; lb = b - nb0;           in = i1; n = n1; }
    else if (b < nb0 + nb1 + nb2){ seg = 2; lb = b - nb0 - nb1;     in = i2; n = n2; }
    else                         { seg = 3; lb = b - nb0 - nb1 - nb2; in = i3; n = n3; }
    int base = lb * SCAN_CHUNK;
    int t = threadIdx.x;
    int s = 0;
    #pragma unroll
    for (int k = 0; k < 8; ++k) {
        int i = base + t * 8 + k;
        if (i < n) s += in[i];
    }
    sdata[t] = s;
    __syncthreads();
    for (int off = 128; off; off >>= 1) {
        if (t < off) sdata[t] += sdata[t + off];
        __syncthreads();
    }
    if (t == 0) bsum[seg * NBMAX + lb] = sdata[0];
}

__global__ void scan_bsums4(int* __restrict__ bsum,
                            int nb0, int nb1, int nb2, int nb3,
                            int* __restrict__ rp0, int m0, int* __restrict__ rp1, int m1,
                            int* __restrict__ rp2, int m2, int* __restrict__ rp3, int m3) {
    __shared__ int sdata[NBMAX];
    int seg = blockIdx.x;
    int nb = seg == 0 ? nb0 : seg == 1 ? nb1 : seg == 2 ? nb2 : nb3;
    int* rp = seg == 0 ? rp0 : seg == 1 ? rp1 : seg == 2 ? rp2 : rp3;
    int m  = seg == 0 ? m0  : seg == 1 ? m1  : seg == 2 ? m2  : m3;
    int t = threadIdx.x;
    int v = (t < nb) ? bsum[seg * NBMAX + t] : 0;
    sdata[t] = v;
    __syncthreads();
    for (int off = 1; off < NBMAX; off <<= 1) {
        int add = (t >= off) ? sdata[t - off] : 0;
        __syncthreads();
        sdata[t] += add;
        __syncthreads();
    }
    if (t < nb) bsum[seg * NBMAX + t] = sdata[t] - v;
    if (t == NBMAX - 1) rp[m] = sdata[NBMAX - 1];
}

__global__ void scan_chunks4(const int* __restrict__ i0, int n0, int nb0, int* __restrict__ r0,
                             const int* __restrict__ i1, int n1, int nb1, int* __restrict__ r1,
                             const int* __restrict__ i2, int n2, int nb2, int* __restrict__ r2,
                             const int* __restrict__ i3, int n3, int nb3, int* __restrict__ r3,
                             const int* __restrict__ bsum) {
    __shared__ int sdata[256];
    int b = blockIdx.x, seg, lb; const int* in; int n; int* out;
    if (b < nb0)                 { seg = 0; lb = b;                 in = i0; n = n0; out = r0; }
    else if (b < nb0 + nb1)      { seg = 1; lb = b - nb0;           in = i1; n = n1; out = r1; }
    else if (b < nb0 + nb1 + nb2){ seg = 2; lb = b - nb0 - nb1;     in = i2; n = n2; out = r2; }
    else                         { seg = 3; lb = b - nb0 - nb1 - nb2; in = i3; n = n3; out = r3; }
    int base = lb * SCAN_CHUNK;
    int t = threadIdx.x;
    int loc[8];
    int s = 0;
    #pragma unroll
    for (int k = 0; k < 8; ++k) {
        int i = base + t * 8 + k;
        int v = (i < n) ? in[i] : 0;
        loc[k] = s;
        s += v;
    }
    sdata[t] = s;
    __syncthreads();
    for (int off = 1; off < 256; off <<= 1) {
        int add = (t >= off) ? sdata[t - off] : 0;
        __syncthreads();
        sdata[t] += add;
        __syncthreads();
    }
    int texcl = sdata[t] - s + bsum[seg * NBMAX + lb];
    #pragma unroll
    for (int k = 0; k < 8; ++k) {
        int i = base + t * 8 + k;
        if (i < n) out[i] = texcl + loc[k];
    }
}

__global__ void scatter_dual(const int* __restrict__ rows, const int* __restrict__ cols,
                             const float* __restrict__ vals,
                             const int* __restrict__ rpA, int* __restrict__ curA, int2* __restrict__ eA,
                             const int* __restrict__ rpB, int* __restrict__ curB, int2* __restrict__ eB,
                             long nnz) {
    long idx = blockIdx.x * (long)blockDim.x + threadIdx.x;
    long stride = (long)gridDim.x * blockDim.x;
    for (; idx < nnz; idx += stride) {
        int r = rows[idx];
        int c = cols[idx];
        int vb = __float_as_int(vals[idx]);
        int pa = rpA[r] + atomicAdd(&curA[r], 1);
        eA[pa] = make_int2(c, vb);
        if (eB) {
            int pb = rpB[c] + atomicAdd(&curB[c], 1);
            eB[pb] = make_int2(r, vb);
        }
    }
}

// ---------- tier-3 push fallback ----------

__global__ void spmm_push(const int* __restrict__ rows, const int* __restrict__ cols,
                          const float* __restrict__ vals, const float* __restrict__ x,
                          float* __restrict__ out, long nnz) {
    long idx = blockIdx.x * (long)blockDim.x + threadIdx.x;
    long stride = (long)gridDim.x * blockDim.x;
    long total = nnz << 6;
    for (; idx < total; idx += stride) {
        long e = idx >> 6;
        int d = (int)(idx & 63);
        int r = rows[e];
        int c = cols[e];
        float v = vals[e];
        atomicAdd(&out[(long)r * DDIM + d], v * x[(long)c * DDIM + d]);
    }
}

static inline int nblk(long threads, long cap) {
    long b = (threads + BLOCK - 1) / BLOCK;
    if (b > cap) b = cap;
    if (b < 1) b = 1;
    return (int)b;
}

extern "C" void kernel_launch(void* const* d_in, const int* in_sizes, int n_in,
                              void* d_out, int out_size, void* d_ws, size_t ws_size,
                              hipStream_t stream) {
    const float* user_emb = (const float*)d_in[0];
    const float* item_emb = (const float*)d_in[1];
    const float* du       = (const float*)d_in[2];
    const float* dv       = (const float*)d_in[3];
    const float* ui_vals  = (const float*)d_in[4];
    const float* uu_vals  = (const float*)d_in[5];
    const float* vv_vals  = (const float*)d_in[6];
    const int*   ui_rows  = (const int*)d_in[7];
    const int*   ui_cols  = (const int*)d_in[8];
    const int*   uu_rows  = (const int*)d_in[9];
    const int*   uu_cols  = (const int*)d_in[10];
    const int*   vv_rows  = (const int*)d_in[11];
    const int*   vv_cols  = (const int*)d_in[12];
    const int*   users    = (const int*)d_in[13];
    const int*   items    = (const int*)d_in[14];

    const int U = in_sizes[2];
    const int I = in_sizes[3];
    const int nnz_ui = in_sizes[4];
    const int nnz_uu = in_sizes[5];
    const int nnz_vv = in_sizes[6];
    const int batch = in_sizes[13];

    const long UD = (long)U * DDIM;
    const long ID = (long)I * DDIM;
    const long nnz_tot = (long)nnz_ui * 2 + nnz_uu + nnz_vv;

    float* gamma = (float*)d_out;
    char* p = (char*)d_ws;
    int gb = (batch * DDIM + BLOCK - 1) / BLOCK;

    auto al = [](size_t x) { return (x + 255) & ~(size_t)255; };

    size_t off = 0;
    size_t o_uRaw  = off; off += al(UD * 4);
    size_t o_uAugA = off; off += al(UD * 4);
    size_t o_iAugA = off; off += al(ID * 4);
    size_t o_uacc  = off; off += al((size_t)batch * DDIM * 4);
    size_t o_iacc  = off; off += al((size_t)batch * DDIM * 4);
    const size_t base_end = off;

    float* uRaw  = (float*)(p + o_uRaw);
    float* uAugA = (float*)(p + o_uAugA);
    float* iAugA = (float*)(p + o_iAugA);
    float* uacc  = (float*)(p + o_uacc);
    float* iacc  = (float*)(p + o_iacc);

    // ---- tier 1: bucket build + src-sorted stream + LDS-accumulate pulls ----
    const int nbU = (U + (1 << BSHIFT) - 1) >> BSHIFT;   // 391
    const int nbI = (I + (1 << BSHIFT) - 1) >> BSHIFT;   // 196
    {
        size_t t = base_end;
        size_t o_gcnt   = t; t += al((size_t)4 * NBB * 4);
        size_t o_gbase  = t; t += al((size_t)4 * NBB * 4);
        size_t o_grun   = t; t += al((size_t)4 * NBB * 4);
        size_t o_e_ui   = t; t += al((size_t)nnz_ui * 8);
        size_t o_e_uu   = t; t += al((size_t)nnz_uu * 8);
        size_t o_e_uiT  = t; t += al((size_t)nnz_ui * 8);
        size_t o_e_vv   = t; t += al((size_t)nnz_vv * 8);
        size_t region   = t;
        size_t reg_need_stg = al((size_t)nnz_tot * 8);
        size_t reg_need_aug = al(UD * 4) + al(ID * 4);
        t += (reg_need_stg > reg_need_aug ? reg_need_stg : reg_need_aug);

        bool fits = (t <= ws_size) && nbU <= NBB && nbI <= NBB &&
                    U < (1 << 18) && I < (1 << 18);
        if (fits) {
            int* gcnt    = (int*)(p + o_gcnt);
            int* gbase   = (int*)(p + o_gbase);
            int* grun    = (int*)(p + o_grun);
            int2* e_ui   = (int2*)(p + o_e_ui);
            int2* e_uu   = (int2*)(p + o_e_uu);
            int2* e_uiT  = (int2*)(p + o_e_uiT);
            int2* e_vv   = (int2*)(p + o_e_vv);
            int2* stg    = (int2*)(p + region);
            float* uAugB = (float*)(p + region);            // alias: used only after build
            float* iAugB = (float*)(p + region + al(UD * 4));

            const int tUi = (nnz_ui + TILE - 1) / TILE;
            const int tUu = (nnz_uu + TILE - 1) / TILE;
            const int tVv = (nnz_vv + TILE - 1) / TILE;

            // seg order: 0=ui (dst=user, src=item), 1=uu, 2=uiT (dst=item, src=user), 3=vv
            Seg s0 = { ui_rows, ui_cols, ui_vals, nnz_ui, tUi, 0 };
            Seg s1 = { uu_rows, uu_cols, uu_vals, nnz_uu, tUu, (long)nnz_ui };
            Seg s2 = { ui_cols, ui_rows, ui_vals, nnz_ui, tUi, (long)nnz_ui + nnz_uu };
            Seg s3 = { vv_rows, vv_cols, vv_vals, nnz_vv, tVv, (long)nnz_ui * 2 + nnz_uu };

            hipMemsetAsync(gcnt, 0, (size_t)4 * NBB * 4, stream);
            int nparts = 2 * tUi + tUu + tVv;
            bucket_count<<<nparts, 256, 0, stream>>>(s0, s1, s2, s3, gcnt);
            bucket_scan512<<<4, NBB, 0, stream>>>(gcnt, gbase, grun, nbU, nbU, nbI, nbI);
            bucket_part<<<nparts, 256, 0, stream>>>(s0, s1, s2, s3, grun, stg);

            SegS q0 = { 0,                          e_ui,  nbU };
            SegS q1 = { (long)nnz_ui,               e_uu,  nbU };
            SegS q2 = { (long)nnz_ui + nnz_uu,      e_uiT, nbI };
            SegS q3 = { (long)nnz_ui * 2 + nnz_uu,  e_vv,  nbI };
            bucket_sortsrc<<<2 * (nbU + nbI), 512, SORT_CAP * 8, stream>>>(
                q0, q1, q2, q3, gbase, gcnt, stg);

            // acc init + layer-0 contributions
            hipMemsetAsync(uacc, 0, (size_t)((p + o_iacc + (size_t)batch * DDIM * 4) - (char*)uacc), stream);
            gather_add<<<gb, BLOCK, 0, stream>>>(uacc, user_emb, users, batch);
            gather_add<<<gb, BLOCK, 0, stream>>>(iacc, item_emb, items, batch);

            first_comb4<<<nblk(UD / 4, 4096), BLOCK, 0, stream>>>(
                (float4*)uAugA, (const float4*)user_emb, du, UD / 4);
            first_comb4<<<nblk(ID / 4, 4096), BLOCK, 0, stream>>>(
                (float4*)iAugA, (const float4*)item_emb, dv, ID / 4);

            float* uAugCur = uAugA; float* uAugNxt = uAugB;
            float* iAugCur = iAugA; float* iAugNxt = iAugB;
            const size_t LDSZ = 512 * DDIM * 4;

            for (int layer = 0; layer < 3; ++layer) {
                bool last = (layer == 2);
                spmm_lds_full<<<nbU, 1024, LDSZ, stream>>>(
                    e_ui, gbase + 0 * NBB, gcnt + 0 * NBB, iAugCur,
                    e_uu, gbase + 1 * NBB, gcnt + 1 * NBB, uAugCur,
                    uRaw, last ? nullptr : uAugNxt, du, user_emb, U);
                gather_add<<<gb, BLOCK, 0, stream>>>(uacc, uRaw, users, batch);

                if (!last) {
                    spmm_lds_full<<<nbI, 1024, LDSZ, stream>>>(
                        e_uiT, gbase + 2 * NBB, gcnt + 2 * NBB, uRaw,
                        e_vv,  gbase + 3 * NBB, gcnt + 3 * NBB, iAugCur,
                        nullptr, iAugNxt, dv, item_emb, I);
                    gather_add_corr<<<gb, BLOCK, 0, stream>>>(iacc, iAugNxt, dv, item_emb, items, batch);
                    float* tt;
                    tt = uAugCur; uAugCur = uAugNxt; uAugNxt = tt;
                    tt = iAugCur; iAugCur = iAugNxt; iAugNxt = tt;
                } else {
                    spmm_lds_rows<<<nbI, 1024, LDSZ, stream>>>(
                        e_uiT, gbase + 2 * NBB, gcnt + 2 * NBB, uRaw,
                        e_vv,  gbase + 3 * NBB, gcnt + 3 * NBB, iAugCur,
                        items, iacc, batch);
                }
            }
            final_gamma<<<gb, BLOCK, 0, stream>>>(uacc, iacc, gamma, batch);
            return;
        }
    }

    // ---- tier 2: CSR build via hist+scan+scatter + row pulls (round-8 proven) ----
    {
        size_t t = base_end;
        size_t o_iB2    = t; t += al(ID * 4);
        size_t o_rp_ui  = t; t += al((size_t)(U + 1) * 4);
        size_t o_rp_uu  = t; t += al((size_t)(U + 1) * 4);
        size_t o_rp_uiT = t; t += al((size_t)(I + 1) * 4);
        size_t o_rp_vv  = t; t += al((size_t)(I + 1) * 4);
        size_t o_c_ui   = t; t += al((size_t)U * 4);
        size_t o_c_uu   = t; t += al((size_t)U * 4);
        size_t o_c_uiT  = t; t += al((size_t)I * 4);
        size_t o_c_vv   = t; t += al((size_t)I * 4);
        size_t o_bsum   = t; t += al((size_t)4 * NBMAX * 4);
        size_t o_e_ui2  = t; t += al((size_t)nnz_ui * 8);
        size_t o_e_uiT2 = t; t += al((size_t)nnz_ui * 8);
        size_t o_e_uu2  = t; t += al((size_t)nnz_uu * 8);
        size_t o_e_vv2  = t; t += al((size_t)nnz_vv * 8);

        if (t <= ws_size) {
            float* uA = uRaw; float* uB = uAugA;
            float* iA = iAugA; float* iB = (float*)(p + o_iB2);
            int* rp_ui   = (int*)(p + o_rp_ui);
            int* rp_uu   = (int*)(p + o_rp_uu);
            int* rp_uiT  = (int*)(p + o_rp_uiT);
            int* rp_vv   = (int*)(p + o_rp_vv);
            int* cnt_ui  = (int*)(p + o_c_ui);
            int* cnt_uu  = (int*)(p + o_c_uu);
            int* cnt_uiT = (int*)(p + o_c_uiT);
            int* cnt_vv  = (int*)(p + o_c_vv);
            int* bsum    = (int*)(p + o_bsum);
            int2* e_ui   = (int2*)(p + o_e_ui2);
            int2* e_uiT  = (int2*)(p + o_e_uiT2);
            int2* e_uu   = (int2*)(p + o_e_uu2);
            int2* e_vv   = (int2*)(p + o_e_vv2);

            const int nbU2 = (U + SCAN_CHUNK - 1) / SCAN_CHUNK;
            const int nbI2 = (I + SCAN_CHUNK - 1) / SCAN_CHUNK;
            size_t cnt_span = (size_t)((p + o_c_vv + (size_t)I * 4) - (char*)cnt_ui);

            hipMemsetAsync(cnt_ui, 0, cnt_span, stream);
            hist4<<<nblk((long)nnz_ui * 2 + nnz_uu + nnz_vv, 4096), BLOCK, 0, stream>>>(
                ui_rows, nnz_ui, cnt_ui, uu_rows, nnz_uu, cnt_uu,
                ui_cols, nnz_ui, cnt_uiT, vv_rows, nnz_vv, cnt_vv);
            block_sums4<<<2 * nbU2 + 2 * nbI2, 256, 0, stream>>>(
                cnt_ui, U, nbU2, cnt_uu, U, nbU2, cnt_uiT, I, nbI2, cnt_vv, I, nbI2, bsum);
            scan_bsums4<<<4, NBMAX, 0, stream>>>(
                bsum, nbU2, nbU2, nbI2, nbI2, rp_ui, U, rp_uu, U, rp_uiT, I, rp_vv, I);
            scan_chunks4<<<2 * nbU2 + 2 * nbI2, 256, 0, stream>>>(
                cnt_ui, U, nbU2, rp_ui, cnt_uu, U, nbU2, rp_uu,
                cnt_uiT, I, nbI2, rp_uiT, cnt_vv, I, nbI2, rp_vv, bsum);
            hipMemsetAsync(cnt_ui, 0, cnt_span, stream);
            scatter_dual<<<nblk(nnz_ui, 4096), BLOCK, 0, stream>>>(
                ui_rows, ui_cols, ui_vals, rp_ui, cnt_ui, e_ui, rp_uiT, cnt_uiT, e_uiT, nnz_ui);
            scatter_dual<<<nblk(nnz_uu, 4096), BLOCK, 0, stream>>>(
                uu_rows, uu_cols, uu_vals, rp_uu, cnt_uu, e_uu, nullptr, nullptr, nullptr, nnz_uu);
            scatter_dual<<<nblk(nnz_vv, 4096), BLOCK, 0, stream>>>(
                vv_rows, vv_cols, vv_vals, rp_vv, cnt_vv, e_vv, nullptr, nullptr, nullptr, nnz_vv);

            hipMemsetAsync(uacc, 0, (size_t)((p + o_iacc + (size_t)batch * DDIM * 4) - (char*)uacc), stream);
            gather_add<<<gb, BLOCK, 0, stream>>>(uacc, user_emb, users, batch);
            gather_add<<<gb, BLOCK, 0, stream>>>(iacc, item_emb, items, batch);

            first_comb4<<<nblk(UD / 4, 4096), BLOCK, 0, stream>>>(
                (float4*)uA, (const float4*)user_emb, du, UD / 4);
            first_comb4<<<nblk(ID / 4, 4096), BLOCK, 0, stream>>>(
                (float4*)iA, (const float4*)item_emb, dv, ID / 4);

            float* ucur = uA; float* unext = uB;
            float* icur = iA; float* inext = iB;
            int ub = (int)((UD + BLOCK - 1) / BLOCK);
            int ib = (int)((ID + BLOCK - 1) / BLOCK);

            for (int layer = 0; layer < 3; ++layer) {
                if (layer > 0) {
                    add_scaled4<<<nblk(UD / 4, 4096), BLOCK, 0, stream>>>(
                        (float4*)ucur, (const float4*)user_emb, du, UD / 4);
                    add_scaled4<<<nblk(ID / 4, 4096), BLOCK, 0, stream>>>(
                        (float4*)icur, (const float4*)item_emb, dv, ID / 4);
                }
                pull2csr<<<ub, BLOCK, 0, stream>>>(rp_ui, e_ui, icur, rp_uu, e_uu, ucur,
                                                   unext, nullptr, nullptr, nullptr, U);
                gather_add<<<gb, BLOCK, 0, stream>>>(uacc, unext, users, batch);
                if (layer < 2) {
                    pull2csr<<<ib, BLOCK, 0, stream>>>(rp_uiT, e_uiT, unext, rp_vv, e_vv, icur,
                                                       inext, nullptr, nullptr, nullptr, I);
                    gather_add<<<gb, BLOCK, 0, stream>>>(iacc, inext, items, batch);
                } else {
                    pull2csr_rows<<<gb, BLOCK, 0, stream>>>(rp_uiT, e_uiT, unext, rp_vv, e_vv, icur,
                                                            items, iacc, batch);
                }
                float* tt;
                tt = ucur; ucur = unext; unext = tt;
                tt = icur; icur = inext; inext = tt;
            }
            final_gamma<<<gb, BLOCK, 0, stream>>>(uacc, iacc, gamma, batch);
            return;
        }
    }

    // ---- tier 3: push-atomic fallback ----
    {
        float* uA = uRaw; float* uB = uAugA;
        float* iA = iAugA; float* iB = (float*)(p + base_end);

        hipMemsetAsync(uacc, 0, (size_t)batch * DDIM * sizeof(float) * 2, stream);
        gather_add<<<gb, BLOCK, 0, stream>>>(uacc, user_emb, users, batch);
        gather_add<<<gb, BLOCK, 0, stream>>>(iacc, item_emb, items, batch);

        first_comb4<<<nblk(UD / 4, 4096), BLOCK, 0, stream>>>(
            (float4*)uA, (const float4*)user_emb, du, UD / 4);
        first_comb4<<<nblk(ID / 4, 4096), BLOCK, 0, stream>>>(
            (float4*)iA, (const float4*)item_emb, dv, ID / 4);

        float* ucur = uA; float* unext = uB;
        float* icur = iA; float* inext = iB;

        for (int layer = 0; layer < 3; ++layer) {
            if (layer > 0) {
                add_scaled4<<<nblk(UD / 4, 4096), BLOCK, 0, stream>>>(
                    (float4*)ucur, (const float4*)user_emb, du, UD / 4);
                add_scaled4<<<nblk(ID / 4, 4096), BLOCK, 0, stream>>>(
                    (float4*)icur, (const float4*)item_emb, dv, ID / 4);
            }
            hipMemsetAsync(unext, 0, UD * sizeof(float), stream);
            spmm_push<<<nblk((long)nnz_ui << 6, 16384), BLOCK, 0, stream>>>(
                ui_rows, ui_cols, ui_vals, icur, unext, nnz_ui);
            spmm_push<<<nblk((long)nnz_uu << 6, 16384), BLOCK, 0, stream>>>(
                uu_rows, uu_cols, uu_vals, ucur, unext, nnz_uu);
            hipMemsetAsync(inext, 0, ID * sizeof(float), stream);
            spmm_push<<<nblk((long)nnz_vv << 6, 16384), BLOCK, 0, stream>>>(
                vv_rows, vv_cols, vv_vals, icur, inext, nnz_vv);
            spmm_push<<<nblk((long)nnz_ui << 6, 16384), BLOCK, 0, stream>>>(
                ui_cols, ui_rows, ui_vals, unext, inext, nnz_ui);
            gather_add<<<gb, BLOCK, 0, stream>>>(uacc, unext, users, batch);
            gather_add<<<gb, BLOCK, 0, stream>>>(iacc, inext, items, batch);
            float* tt;
            tt = ucur; ucur = unext; unext = tt;
            tt = icur; icur = inext; inext = tt;
        }
        final_gamma<<<gb, BLOCK, 0, stream>>>(uacc, iacc, gamma, batch);
    }
}

// Round 10
// 885.023 us; speedup vs baseline: 9.0079x; 9.0079x over previous
//
#include <hip/hip_runtime.h>

#define BLOCK 256
#define DDIM 64
#define SCAN_CHUNK 2048   // tier-2 scan: 256 threads * 8 elements
#define NBMAX 128         // tier-2 max scan chunks per segment
#define NBB 256           // tier-1 bucket array stride (buckets per segment <= 256)
#define TILE 16384        // tier-1 edges per partition tile (big => coalesced chunk writes)
#define TITER (TILE / 256)
#define RPBMAX 1024       // tier-1 max rows per bucket

// ---------- elementwise / small kernels ----------

__global__ void first_comb4(float4* __restrict__ dst, const float4* __restrict__ emb0,
                            const float* __restrict__ scale, long n4) {
    long idx = blockIdx.x * (long)blockDim.x + threadIdx.x;
    long stride = (long)gridDim.x * blockDim.x;
    for (; idx < n4; idx += stride) {
        float s = 1.0f + scale[idx >> 4];
        float4 e = emb0[idx];
        e.x *= s; e.y *= s; e.z *= s; e.w *= s;
        dst[idx] = e;
    }
}

__global__ void add_scaled4(float4* __restrict__ cur, const float4* __restrict__ emb0,
                            const float* __restrict__ scale, long n4) {
    long idx = blockIdx.x * (long)blockDim.x + threadIdx.x;
    long stride = (long)gridDim.x * blockDim.x;
    for (; idx < n4; idx += stride) {
        float s = scale[idx >> 4];
        float4 e = emb0[idx];
        float4 c = cur[idx];
        c.x += s * e.x; c.y += s * e.y; c.z += s * e.z; c.w += s * e.w;
        cur[idx] = c;
    }
}

__global__ void gather_add(float* __restrict__ acc, const float* __restrict__ emb,
                           const int* __restrict__ idxs, int batch) {
    int t = blockIdx.x * blockDim.x + threadIdx.x;
    if (t >= batch * DDIM) return;
    int b = t >> 6;
    acc[t] += emb[(long)idxs[b] * DDIM + (t & 63)];
}

// acc += aug[row] - scale[row]*emb0[row]   (recover raw layer output at sampled rows)
__global__ void gather_add_corr(float* __restrict__ acc, const float* __restrict__ aug,
                                const float* __restrict__ scale, const float* __restrict__ emb0,
                                const int* __restrict__ idxs, int batch) {
    int t = blockIdx.x * blockDim.x + threadIdx.x;
    if (t >= batch * DDIM) return;
    int b = t >> 6;
    long r = idxs[b];
    long o = r * DDIM + (t & 63);
    acc[t] += aug[o] - scale[r] * emb0[o];
}

__global__ void final_gamma(const float* __restrict__ uacc, const float* __restrict__ iacc,
                            float* __restrict__ out, int batch) {
    int t = blockIdx.x * blockDim.x + threadIdx.x;
    if (t >= batch * DDIM) return;
    int b = t >> 6;
    float v = uacc[t] * iacc[t];
    #pragma unroll
    for (int off = 32; off; off >>= 1) v += __shfl_down(v, off, 64);
    if ((threadIdx.x & 63) == 0) out[b] = v * (1.0f / 16.0f);
}

// ---------- tier-1 build: bucket partition (counting-sort), no random-line atomics ----------

struct Seg {   // partition source descriptor
    const int*   keys;   // bucketed index (row of the target CSR)
    const int*   other;  // the other endpoint
    const float* vals;
    int n;               // edge count
    int shift;           // bucket = key >> shift; row_local = key & ((1<<shift)-1)
    int tiles;           // ceil(n / TILE)
    long stg_off;        // segment offset into staging (elements)
};

struct SegOut {  // per-bucket CSR finalize descriptor
    int R;        // rows
    int shift;
    int nb;       // bucket count
    long stg_off;
    int2* eout;   // packed (col,val)
    int* rp;      // row pointer [R+1]
};

// P0: count edges per (segment, bucket). One block = one tile.
__global__ void bucket_count(Seg s0, Seg s1, Seg s2, Seg s3, int* __restrict__ gcnt) {
    __shared__ int h[NBB];
    int b = blockIdx.x; Seg s; int seg;
    if (b < s0.tiles)                              { s = s0; seg = 0; }
    else if (b < s0.tiles + s1.tiles)              { s = s1; seg = 1; b -= s0.tiles; }
    else if (b < s0.tiles + s1.tiles + s2.tiles)   { s = s2; seg = 2; b -= s0.tiles + s1.tiles; }
    else                                           { s = s3; seg = 3; b -= s0.tiles + s1.tiles + s2.tiles; }
    int tid = threadIdx.x;
    h[tid] = 0;
    __syncthreads();
    int base = b * TILE;
    for (int k = 0; k < TITER; ++k) {
        int i = base + k * 256 + tid;
        if (i < s.n) atomicAdd(&h[s.keys[i] >> s.shift], 1);
    }
    __syncthreads();
    if (h[tid]) atomicAdd(&gcnt[seg * NBB + tid], h[tid]);
}

// P0s: per-segment exclusive scan of bucket counts -> gbase (fixed) and grun (running cursor).
__global__ void bucket_scan(const int* __restrict__ gcnt, int* __restrict__ gbase, int* __restrict__ grun,
                            int nb0, int nb1, int nb2, int nb3,
                            int* rpe0, int* rpe1, int* rpe2, int* rpe3,
                            int nnz0, int nnz1, int nnz2, int nnz3) {
    __shared__ int part[256];
    int tid = threadIdx.x;
    for (int seg = 0; seg < 4; ++seg) {
        int nb = seg == 0 ? nb0 : seg == 1 ? nb1 : seg == 2 ? nb2 : nb3;
        int v = (tid < nb) ? gcnt[seg * NBB + tid] : 0;
        part[tid] = v;
        __syncthreads();
        for (int o = 1; o < 256; o <<= 1) {
            int a = (tid >= o) ? part[tid - o] : 0;
            __syncthreads();
            part[tid] += a;
            __syncthreads();
        }
        int excl = part[tid] - v;
        if (tid < nb) { gbase[seg * NBB + tid] = excl; grun[seg * NBB + tid] = excl; }
        __syncthreads();
    }
    if (tid == 0) { *rpe0 = nnz0; *rpe1 = nnz1; *rpe2 = nnz2; *rpe3 = nnz3; }
}

// P1: partition edges into bucket-contiguous staging. One block = one tile.
__global__ void bucket_part(Seg s0, Seg s1, Seg s2, Seg s3,
                            int* __restrict__ grun, int2* __restrict__ stg) {
    __shared__ int h[NBB];
    __shared__ int hb[NBB];
    int b = blockIdx.x; Seg s; int seg;
    if (b < s0.tiles)                              { s = s0; seg = 0; }
    else if (b < s0.tiles + s1.tiles)              { s = s1; seg = 1; b -= s0.tiles; }
    else if (b < s0.tiles + s1.tiles + s2.tiles)   { s = s2; seg = 2; b -= s0.tiles + s1.tiles; }
    else                                           { s = s3; seg = 3; b -= s0.tiles + s1.tiles + s2.tiles; }
    int tid = threadIdx.x;
    h[tid] = 0;
    __syncthreads();
    int base = b * TILE;
    for (int k = 0; k < TITER; ++k) {
        int i = base + k * 256 + tid;
        if (i < s.n) atomicAdd(&h[s.keys[i] >> s.shift], 1);
    }
    __syncthreads();
    int c = h[tid];
    if (c) hb[tid] = atomicAdd(&grun[seg * NBB + tid], c);
    h[tid] = 0;   // reuse as within-chunk cursor
    __syncthreads();
    int mask = (1 << s.shift) - 1;
    int2* out = stg + s.stg_off;
    for (int k = 0; k < TITER; ++k) {
        int i = base + k * 256 + tid;
        if (i < s.n) {
            int key = s.keys[i];
            int bk = key >> s.shift;
            int rl = key & mask;
            int slot = atomicAdd(&h[bk], 1);
            out[hb[bk] + slot] = make_int2((rl << 18) | s.other[i], __float_as_int(s.vals[i]));
        }
    }
}

// P2: per-bucket CSR finalize.
__global__ void bucket_csr(SegOut s0, SegOut s1, SegOut s2, SegOut s3,
                           const int* __restrict__ gbase, const int* __restrict__ gcnt,
                           const int2* __restrict__ stg) {
    __shared__ int cnt[RPBMAX];
    __shared__ int part[256];
    int b = blockIdx.x; SegOut s; int seg;
    if (b < s0.nb)                     { s = s0; seg = 0; }
    else if (b < s0.nb + s1.nb)        { s = s1; seg = 1; b -= s0.nb; }
    else if (b < s0.nb + s1.nb + s2.nb){ s = s2; seg = 2; b -= s0.nb + s1.nb; }
    else                               { s = s3; seg = 3; b -= s0.nb + s1.nb + s2.nb; }
    int tid = threadIdx.x;
    int RPB = 1 << s.shift;
    int lo = b << s.shift;
    int nloc = s.R - lo; if (nloc > RPB) nloc = RPB;
    int start = gbase[seg * NBB + b];
    int end = start + gcnt[seg * NBB + b];
    const int2* in = stg + s.stg_off;

    for (int i = tid; i < RPBMAX; i += 256) cnt[i] = 0;
    __syncthreads();
    for (int i = start + tid; i < end; i += 256) {
        unsigned x = (unsigned)in[i].x;
        atomicAdd(&cnt[x >> 18], 1);
    }
    __syncthreads();
    int loc[4]; int ssum = 0;
    #pragma unroll
    for (int j = 0; j < 4; ++j) { loc[j] = ssum; ssum += cnt[tid * 4 + j]; }
    part[tid] = ssum;
    __syncthreads();
    for (int o = 1; o < 256; o <<= 1) {
        int a = (tid >= o) ? part[tid - o] : 0;
        __syncthreads();
        part[tid] += a;
        __syncthreads();
    }
    int excl = part[tid] - ssum;
    #pragma unroll
    for (int j = 0; j < 4; ++j) {
        int idx = tid * 4 + j;
        int o = excl + loc[j];
        if (idx < nloc) s.rp[lo + idx] = start + o;
        cnt[idx] = o;   // becomes scatter cursor
    }
    __syncthreads();
    for (int i = start + tid; i < end; i += 256) {
        int2 pr = in[i];
        unsigned x = (unsigned)pr.x;
        int pos = atomicAdd(&cnt[x >> 18], 1);
        s.eout[start + pos] = make_int2((int)(x & 0x3FFFFu), pr.y);
    }
}

// ---------- pull-style fused SpMM (packed edges, 16-lane float4 groups, 4 edges/group/step) ----------

__device__ __forceinline__ void row_part_csr(const int* __restrict__ rp,
                                             const int2* __restrict__ ee,
                                             const float* __restrict__ x,
                                             int row, int lane,
                                             float4& acc0, float4& acc1) {
    const int l16 = lane & 15;
    const int g = lane >> 4;
    const float4* x4 = (const float4*)x;
    int s = rp[row], e = rp[row + 1];
    for (int j = s; j < e; j += 64) {
        int cnt = e - j; if (cnt > 64) cnt = 64;
        int myc = 0; float myv = 0.0f;
        if (lane < cnt) { int2 pr = ee[j + lane]; myc = pr.x; myv = __int_as_float(pr.y); }
        int steps = (cnt + 15) >> 4;
        for (int st = 0; st < steps; ++st) {
            int t0 = st * 16 + g;
            int t1 = t0 + 4, t2 = t0 + 8, t3 = t0 + 12;
            int   c0 = __shfl(myc, t0, 64); float w0 = __shfl(myv, t0, 64);
            int   c1 = __shfl(myc, t1, 64); float w1 = __shfl(myv, t1, 64);
            int   c2 = __shfl(myc, t2, 64); float w2 = __shfl(myv, t2, 64);
            int   c3 = __shfl(myc, t3, 64); float w3 = __shfl(myv, t3, 64);
            bool ok0 = t0 < cnt, ok1 = t1 < cnt, ok2 = t2 < cnt, ok3 = t3 < cnt;
            c0 = ok0 ? c0 : 0; w0 = ok0 ? w0 : 0.0f;
            c1 = ok1 ? c1 : 0; w1 = ok1 ? w1 : 0.0f;
            c2 = ok2 ? c2 : 0; w2 = ok2 ? w2 : 0.0f;
            c3 = ok3 ? c3 : 0; w3 = ok3 ? w3 : 0.0f;
            float4 xv0 = x4[(long)c0 * 16 + l16];
            float4 xv1 = x4[(long)c1 * 16 + l16];
            float4 xv2 = x4[(long)c2 * 16 + l16];
            float4 xv3 = x4[(long)c3 * 16 + l16];
            acc0.x += w0 * xv0.x; acc0.y += w0 * xv0.y; acc0.z += w0 * xv0.z; acc0.w += w0 * xv0.w;
            acc1.x += w1 * xv1.x; acc1.y += w1 * xv1.y; acc1.z += w1 * xv1.z; acc1.w += w1 * xv1.w;
            acc0.x += w2 * xv2.x; acc0.y += w2 * xv2.y; acc0.z += w2 * xv2.z; acc0.w += w2 * xv2.w;
            acc1.x += w3 * xv3.x; acc1.y += w3 * xv3.y; acc1.z += w3 * xv3.z; acc1.w += w3 * xv3.w;
        }
    }
}

__device__ __forceinline__ float4 group_reduce(float4 a) {
    a.x += __shfl_xor(a.x, 16, 64); a.y += __shfl_xor(a.y, 16, 64);
    a.z += __shfl_xor(a.z, 16, 64); a.w += __shfl_xor(a.w, 16, 64);
    a.x += __shfl_xor(a.x, 32, 64); a.y += __shfl_xor(a.y, 32, 64);
    a.z += __shfl_xor(a.z, 32, 64); a.w += __shfl_xor(a.w, 32, 64);
    return a;
}

// out_raw (if non-null): raw SpMM result.  out_aug (if non-null): raw + scale[row]*emb0[row]
__global__ void pull2csr(const int* __restrict__ rpA, const int2* __restrict__ eA, const float* __restrict__ xA,
                         const int* __restrict__ rpB, const int2* __restrict__ eB, const float* __restrict__ xB,
                         float* __restrict__ out_raw, float* __restrict__ out_aug,
                         const float* __restrict__ scale, const float* __restrict__ emb0,
                         int nrows) {
    int wave = (int)((blockIdx.x * (long)blockDim.x + threadIdx.x) >> 6);
    int lane = threadIdx.x & 63;
    if (wave >= nrows) return;
    float4 z = make_float4(0.f, 0.f, 0.f, 0.f);
    float4 a0 = z, a1 = z, b0 = z, b1 = z;
    row_part_csr(rpA, eA, xA, wave, lane, a0, a1);
    row_part_csr(rpB, eB, xB, wave, lane, b0, b1);
    a0.x += a1.x; a0.y += a1.y; a0.z += a1.z; a0.w += a1.w;
    b0.x += b1.x; b0.y += b1.y; b0.z += b1.z; b0.w += b1.w;
    a0.x += b0.x; a0.y += b0.y; a0.z += b0.z; a0.w += b0.w;
    a0 = group_reduce(a0);
    if (lane < 16) {
        long o = (long)wave * 16 + lane;
        if (out_raw) ((float4*)out_raw)[o] = a0;
        if (out_aug) {
            float s = scale[wave];
            float4 e0 = ((const float4*)emb0)[o];
            float4 g = a0;
            g.x += s * e0.x; g.y += s * e0.y; g.z += s * e0.z; g.w += s * e0.w;
            ((float4*)out_aug)[o] = g;
        }
    }
}

__global__ void pull2csr_rows(const int* __restrict__ rpA, const int2* __restrict__ eA, const float* __restrict__ xA,
                              const int* __restrict__ rpB, const int2* __restrict__ eB, const float* __restrict__ xB,
                              const int* __restrict__ rowlist, float* __restrict__ acc, int nlist) {
    int w = (int)((blockIdx.x * (long)blockDim.x + threadIdx.x) >> 6);
    int lane = threadIdx.x & 63;
    if (w >= nlist) return;
    int row = rowlist[w];
    float4 z = make_float4(0.f, 0.f, 0.f, 0.f);
    float4 a0 = z, a1 = z, b0 = z, b1 = z;
    row_part_csr(rpA, eA, xA, row, lane, a0, a1);
    row_part_csr(rpB, eB, xB, row, lane, b0, b1);
    a0.x += a1.x; a0.y += a1.y; a0.z += a1.z; a0.w += a1.w;
    b0.x += b1.x; b0.y += b1.y; b0.z += b1.z; b0.w += b1.w;
    a0.x += b0.x; a0.y += b0.y; a0.z += b0.z; a0.w += b0.w;
    a0 = group_reduce(a0);
    if (lane < 16) {
        float4* acc4 = (float4*)acc;
        float4 cur = acc4[(long)w * 16 + lane];
        cur.x += a0.x; cur.y += a0.y; cur.z += a0.z; cur.w += a0.w;
        acc4[(long)w * 16 + lane] = cur;
    }
}

// ---------- tier-2 CSR build (hist+scan+scatter) ----------

__global__ void hist4(const int* __restrict__ a0, long n0, int* __restrict__ c0,
                      const int* __restrict__ a1, long n1, int* __restrict__ c1,
                      const int* __restrict__ a2, long n2, int* __restrict__ c2,
                      const int* __restrict__ a3, long n3, int* __restrict__ c3) {
    long idx = blockIdx.x * (long)blockDim.x + threadIdx.x;
    long stride = (long)gridDim.x * blockDim.x;
    long t01 = n0 + n1, t012 = n0 + n1 + n2, total = t012 + n3;
    for (; idx < total; idx += stride) {
        if (idx < n0)        atomicAdd(&c0[a0[idx]], 1);
        else if (idx < t01)  atomicAdd(&c1[a1[idx - n0]], 1);
        else if (idx < t012) atomicAdd(&c2[a2[idx - t01]], 1);
        else                 atomicAdd(&c3[a3[idx - t012]], 1);
    }
}

__global__ void block_sums4(const int* __restrict__ i0, int n0, int nb0,
                            const int* __restrict__ i1, int n1, int nb1,
                            const int* __restrict__ i2, int n2, int nb2,
                            const int* __restrict__ i3, int n3, int nb3,
                            int* __restrict__ bsum) {
    __shared__ int sdata[256];
    int b = blockIdx.x, seg, lb; const int* in; int n;
    if (b < nb0)                 { seg = 0; lb = b;                 in = i0; n = n0; }
    else if (b < nb0 + nb1)      { seg = 1; lb = b - nb0;           in = i1; n = n1; }
    else if (b < nb0 + nb1 + nb2){ seg = 2; lb = b - nb0 - nb1;     in = i2; n = n2; }
    else                         { seg = 3; lb = b - nb0 - nb1 - nb2; in = i3; n = n3; }
    int base = lb * SCAN_CHUNK;
    int t = threadIdx.x;
    int s = 0;
    #pragma unroll
    for (int k = 0; k < 8; ++k) {
        int i = base + t * 8 + k;
        if (i < n) s += in[i];
    }
    sdata[t] = s;
    __syncthreads();
    for (int off = 128; off; off >>= 1) {
        if (t < off) sdata[t] += sdata[t + off];
        __syncthreads();
    }
    if (t == 0) bsum[seg * NBMAX + lb] = sdata[0];
}

__global__ void scan_bsums4(int* __restrict__ bsum,
                            int nb0, int nb1, int nb2, int nb3,
                            int* __restrict__ rp0, int m0, int* __restrict__ rp1, int m1,
                            int* __restrict__ rp2, int m2, int* __restrict__ rp3, int m3) {
    __shared__ int sdata[NBMAX];
    int seg = blockIdx.x;
    int nb = seg == 0 ? nb0 : seg == 1 ? nb1 : seg == 2 ? nb2 : nb3;
    int* rp = seg == 0 ? rp0 : seg == 1 ? rp1 : seg == 2 ? rp2 : rp3;
    int m  = seg == 0 ? m0  : seg == 1 ? m1  : seg == 2 ? m2  : m3;
    int t = threadIdx.x;
    int v = (t < nb) ? bsum[seg * NBMAX + t] : 0;
    sdata[t] = v;
    __syncthreads();
    for (int off = 1; off < NBMAX; off <<= 1) {
        int add = (t >= off) ? sdata[t - off] : 0;
        __syncthreads();
        sdata[t] += add;
        __syncthreads();
    }
    if (t < nb) bsum[seg * NBMAX + t] = sdata[t] - v;
    if (t == NBMAX - 1) rp[m] = sdata[NBMAX - 1];
}

__global__ void scan_chunks4(const int* __restrict__ i0, int n0, int nb0, int* __restrict__ r0,
                             const int* __restrict__ i1, int n1, int nb1, int* __restrict__ r1,
                             const int* __restrict__ i2, int n2, int nb2, int* __restrict__ r2,
                             const int* __restrict__ i3, int n3, int nb3, int* __restrict__ r3,
                             const int* __restrict__ bsum) {
    __shared__ int sdata[256];
    int b = blockIdx.x, seg, lb; const int* in; int n; int* out;
    if (b < nb0)                 { seg = 0; lb = b;                 in = i0; n = n0; out = r0; }
    else if (b < nb0 + nb1)      { seg = 1; lb = b - nb0;           in = i1; n = n1; out = r1; }
    else if (b < nb0 + nb1 + nb2){ seg = 2; lb = b - nb0 - nb1;     in = i2; n = n2; out = r2; }
    else                         { seg = 3; lb = b - nb0 - nb1 - nb2; in = i3; n = n3; out = r3; }
    int base = lb * SCAN_CHUNK;
    int t = threadIdx.x;
    int loc[8];
    int s = 0;
    #pragma unroll
    for (int k = 0; k < 8; ++k) {
        int i = base + t * 8 + k;
        int v = (i < n) ? in[i] : 0;
        loc[k] = s;
        s += v;
    }
    sdata[t] = s;
    __syncthreads();
    for (int off = 1; off < 256; off <<= 1) {
        int add = (t >= off) ? sdata[t - off] : 0;
        __syncthreads();
        sdata[t] += add;
        __syncthreads();
    }
    int texcl = sdata[t] - s + bsum[seg * NBMAX + lb];
    #pragma unroll
    for (int k = 0; k < 8; ++k) {
        int i = base + t * 8 + k;
        if (i < n) out[i] = texcl + loc[k];
    }
}

__global__ void scatter_dual(const int* __restrict__ rows, const int* __restrict__ cols,
                             const float* __restrict__ vals,
                             const int* __restrict__ rpA, int* __restrict__ curA, int2* __restrict__ eA,
                             const int* __restrict__ rpB, int* __restrict__ curB, int2* __restrict__ eB,
                             long nnz) {
    long idx = blockIdx.x * (long)blockDim.x + threadIdx.x;
    long stride = (long)gridDim.x * blockDim.x;
    for (; idx < nnz; idx += stride) {
        int r = rows[idx];
        int c = cols[idx];
        int vb = __float_as_int(vals[idx]);
        int pa = rpA[r] + atomicAdd(&curA[r], 1);
        eA[pa] = make_int2(c, vb);
        if (eB) {
            int pb = rpB[c] + atomicAdd(&curB[c], 1);
            eB[pb] = make_int2(r, vb);
        }
    }
}

// ---------- tier-3 push fallback ----------

__global__ void spmm_push(const int* __restrict__ rows, const int* __restrict__ cols,
                          const float* __restrict__ vals, const float* __restrict__ x,
                          float* __restrict__ out, long nnz) {
    long idx = blockIdx.x * (long)blockDim.x + threadIdx.x;
    long stride = (long)gridDim.x * blockDim.x;
    long total = nnz << 6;
    for (; idx < total; idx += stride) {
        long e = idx >> 6;
        int d = (int)(idx & 63);
        int r = rows[e];
        int c = cols[e];
        float v = vals[e];
        atomicAdd(&out[(long)r * DDIM + d], v * x[(long)c * DDIM + d]);
    }
}

static inline int nblk(long threads, long cap) {
    long b = (threads + BLOCK - 1) / BLOCK;
    if (b > cap) b = cap;
    if (b < 1) b = 1;
    return (int)b;
}

extern "C" void kernel_launch(void* const* d_in, const int* in_sizes, int n_in,
                              void* d_out, int out_size, void* d_ws, size_t ws_size,
                              hipStream_t stream) {
    const float* user_emb = (const float*)d_in[0];
    const float* item_emb = (const float*)d_in[1];
    const float* du       = (const float*)d_in[2];
    const float* dv       = (const float*)d_in[3];
    const float* ui_vals  = (const float*)d_in[4];
    const float* uu_vals  = (const float*)d_in[5];
    const float* vv_vals  = (const float*)d_in[6];
    const int*   ui_rows  = (const int*)d_in[7];
    const int*   ui_cols  = (const int*)d_in[8];
    const int*   uu_rows  = (const int*)d_in[9];
    const int*   uu_cols  = (const int*)d_in[10];
    const int*   vv_rows  = (const int*)d_in[11];
    const int*   vv_cols  = (const int*)d_in[12];
    const int*   users    = (const int*)d_in[13];
    const int*   items    = (const int*)d_in[14];

    const int U = in_sizes[2];
    const int I = in_sizes[3];
    const int nnz_ui = in_sizes[4];
    const int nnz_uu = in_sizes[5];
    const int nnz_vv = in_sizes[6];
    const int batch = in_sizes[13];

    const long UD = (long)U * DDIM;
    const long ID = (long)I * DDIM;
    const long nnz_tot = (long)nnz_ui * 2 + nnz_uu + nnz_vv;

    float* gamma = (float*)d_out;
    char* p = (char*)d_ws;
    int gb = (batch * DDIM + BLOCK - 1) / BLOCK;

    auto al = [](size_t x) { return (x + 255) & ~(size_t)255; };

    // common buffers
    size_t off = 0;
    size_t o_uRaw  = off; off += al(UD * 4);
    size_t o_uAugA = off; off += al(UD * 4);
    size_t o_iAugA = off; off += al(ID * 4);
    size_t o_uacc  = off; off += al((size_t)batch * DDIM * 4);
    size_t o_iacc  = off; off += al((size_t)batch * DDIM * 4);
    const size_t base_end = off;

    float* uRaw  = (float*)(p + o_uRaw);
    float* uAugA = (float*)(p + o_uAugA);
    float* iAugA = (float*)(p + o_iAugA);
    float* uacc  = (float*)(p + o_uacc);
    float* iacc  = (float*)(p + o_iacc);

    // ---- tier 1: bucket-partition CSR build + fused pulls ----
    const int shiftU = 10, shiftI = 9;                // 1024 / 512 rows per bucket
    const int nbU = (U + (1 << shiftU) - 1) >> shiftU;
    const int nbI = (I + (1 << shiftI) - 1) >> shiftI;
    {
        size_t t = base_end;
        size_t o_rp_ui  = t; t += al((size_t)(U + 1) * 4);
        size_t o_rp_uu  = t; t += al((size_t)(U + 1) * 4);
        size_t o_rp_uiT = t; t += al((size_t)(I + 1) * 4);
        size_t o_rp_vv  = t; t += al((size_t)(I + 1) * 4);
        size_t o_gcnt   = t; t += al((size_t)4 * NBB * 4);
        size_t o_gbase  = t; t += al((size_t)4 * NBB * 4);
        size_t o_grun   = t; t += al((size_t)4 * NBB * 4);
        size_t o_e_ui   = t; t += al((size_t)nnz_ui * 8);
        size_t o_e_uu   = t; t += al((size_t)nnz_uu * 8);
        size_t o_e_uiT  = t; t += al((size_t)nnz_ui * 8);
        size_t o_e_vv   = t; t += al((size_t)nnz_vv * 8);
        // region shared by staging (build phase) and AugB buffers (iteration phase)
        size_t region   = t;
        size_t reg_need_stg = al((size_t)nnz_tot * 8);
        size_t reg_need_aug = al(UD * 4) + al(ID * 4);
        t += (reg_need_stg > reg_need_aug ? reg_need_stg : reg_need_aug);

        bool fits = (t <= ws_size) && nbU <= NBB && nbI <= NBB &&
                    U < (1 << 18) && I < (1 << 18);
        if (fits) {
            int* rp_ui   = (int*)(p + o_rp_ui);
            int* rp_uu   = (int*)(p + o_rp_uu);
            int* rp_uiT  = (int*)(p + o_rp_uiT);
            int* rp_vv   = (int*)(p + o_rp_vv);
            int* gcnt    = (int*)(p + o_gcnt);
            int* gbase   = (int*)(p + o_gbase);
            int* grun    = (int*)(p + o_grun);
            int2* e_ui   = (int2*)(p + o_e_ui);
            int2* e_uu   = (int2*)(p + o_e_uu);
            int2* e_uiT  = (int2*)(p + o_e_uiT);
            int2* e_vv   = (int2*)(p + o_e_vv);
            int2* stg    = (int2*)(p + region);
            float* uAugB = (float*)(p + region);            // alias: used only after build done
            float* iAugB = (float*)(p + region + al(UD * 4));

            const int tUi = (nnz_ui + TILE - 1) / TILE;
            const int tUu = (nnz_uu + TILE - 1) / TILE;
            const int tVv = (nnz_vv + TILE - 1) / TILE;

            Seg s0 = { ui_rows, ui_cols, ui_vals, nnz_ui, shiftU, tUi, 0 };
            Seg s1 = { uu_rows, uu_cols, uu_vals, nnz_uu, shiftU, tUu, (long)nnz_ui };
            Seg s2 = { ui_cols, ui_rows, ui_vals, nnz_ui, shiftI, tUi, (long)nnz_ui + nnz_uu };
            Seg s3 = { vv_rows, vv_cols, vv_vals, nnz_vv, shiftI, tVv, (long)nnz_ui * 2 + nnz_uu };

            hipMemsetAsync(gcnt, 0, (size_t)4 * NBB * 4, stream);

            int nparts = 2 * tUi + tUu + tVv;
            bucket_count<<<nparts, 256, 0, stream>>>(s0, s1, s2, s3, gcnt);
            bucket_scan<<<1, 256, 0, stream>>>(gcnt, gbase, grun,
                                               nbU, nbU, nbI, nbI,
                                               rp_ui + U, rp_uu + U, rp_uiT + I, rp_vv + I,
                                               nnz_ui, nnz_uu, nnz_ui, nnz_vv);
            bucket_part<<<nparts, 256, 0, stream>>>(s0, s1, s2, s3, grun, stg);

            SegOut q0 = { U, shiftU, nbU, 0,                          e_ui,  rp_ui  };
            SegOut q1 = { U, shiftU, nbU, (long)nnz_ui,               e_uu,  rp_uu  };
            SegOut q2 = { I, shiftI, nbI, (long)nnz_ui + nnz_uu,      e_uiT, rp_uiT };
            SegOut q3 = { I, shiftI, nbI, (long)nnz_ui * 2 + nnz_uu,  e_vv,  rp_vv  };
            bucket_csr<<<2 * (nbU + nbI), 256, 0, stream>>>(q0, q1, q2, q3, gbase, gcnt, stg);

            // acc init + layer-0 contributions (original embeddings)
            hipMemsetAsync(uacc, 0, (size_t)((p + o_iacc + (size_t)batch * DDIM * 4) - (char*)uacc), stream);
            gather_add<<<gb, BLOCK, 0, stream>>>(uacc, user_emb, users, batch);
            gather_add<<<gb, BLOCK, 0, stream>>>(iacc, item_emb, items, batch);

            // layer-0 gather sources: emb0 * (1 + d)
            first_comb4<<<nblk(UD / 4, 4096), BLOCK, 0, stream>>>(
                (float4*)uAugA, (const float4*)user_emb, du, UD / 4);
            first_comb4<<<nblk(ID / 4, 4096), BLOCK, 0, stream>>>(
                (float4*)iAugA, (const float4*)item_emb, dv, ID / 4);

            float* uAugCur = uAugA; float* uAugNxt = uAugB;
            float* iAugCur = iAugA; float* iAugNxt = iAugB;

            int ub = (int)((UD + BLOCK - 1) / BLOCK);
            int ib = (int)((ID + BLOCK - 1) / BLOCK);

            for (int layer = 0; layer < 3; ++layer) {
                bool last = (layer == 2);
                // users_new = A_ui @ I_in + A_uu @ U_in ; aug = users_new + du*u0
                pull2csr<<<ub, BLOCK, 0, stream>>>(
                    rp_ui, e_ui, iAugCur, rp_uu, e_uu, uAugCur,
                    uRaw, last ? nullptr : uAugNxt, du, user_emb, U);
                gather_add<<<gb, BLOCK, 0, stream>>>(uacc, uRaw, users, batch);

                if (!last) {
                    // items_new = A_uiT @ users_new(raw) + A_vv @ I_in ; write aug only
                    pull2csr<<<ib, BLOCK, 0, stream>>>(
                        rp_uiT, e_uiT, uRaw, rp_vv, e_vv, iAugCur,
                        nullptr, iAugNxt, dv, item_emb, I);
                    gather_add_corr<<<gb, BLOCK, 0, stream>>>(iacc, iAugNxt, dv, item_emb, items, batch);
                    float* tt;
                    tt = uAugCur; uAugCur = uAugNxt; uAugNxt = tt;
                    tt = iAugCur; iAugCur = iAugNxt; iAugNxt = tt;
                } else {
                    // last layer: items only needed at sampled rows
                    pull2csr_rows<<<gb, BLOCK, 0, stream>>>(
                        rp_uiT, e_uiT, uRaw, rp_vv, e_vv, iAugCur, items, iacc, batch);
                }
            }
            final_gamma<<<gb, BLOCK, 0, stream>>>(uacc, iacc, gamma, batch);
            return;
        }
    }

    // ---- tier 2: CSR build via hist+scan+scatter (round-4 proven structure) ----
    {
        size_t t = base_end;
        size_t o_iB2    = t; t += al(ID * 4);       // second item ping-pong buffer
        size_t o_rp_ui  = t; t += al((size_t)(U + 1) * 4);
        size_t o_rp_uu  = t; t += al((size_t)(U + 1) * 4);
        size_t o_rp_uiT = t; t += al((size_t)(I + 1) * 4);
        size_t o_rp_vv  = t; t += al((size_t)(I + 1) * 4);
        size_t o_c_ui   = t; t += al((size_t)U * 4);
        size_t o_c_uu   = t; t += al((size_t)U * 4);
        size_t o_c_uiT  = t; t += al((size_t)I * 4);
        size_t o_c_vv   = t; t += al((size_t)I * 4);
        size_t o_bsum   = t; t += al((size_t)4 * NBMAX * 4);
        size_t o_e_ui2  = t; t += al((size_t)nnz_ui * 8);
        size_t o_e_uiT2 = t; t += al((size_t)nnz_ui * 8);
        size_t o_e_uu2  = t; t += al((size_t)nnz_uu * 8);
        size_t o_e_vv2  = t; t += al((size_t)nnz_vv * 8);

        if (t <= ws_size) {
            float* uA = uRaw; float* uB = uAugA;
            float* iA = iAugA; float* iB = (float*)(p + o_iB2);
            int* rp_ui   = (int*)(p + o_rp_ui);
            int* rp_uu   = (int*)(p + o_rp_uu);
            int* rp_uiT  = (int*)(p + o_rp_uiT);
            int* rp_vv   = (int*)(p + o_rp_vv);
            int* cnt_ui  = (int*)(p + o_c_ui);
            int* cnt_uu  = (int*)(p + o_c_uu);
            int* cnt_uiT = (int*)(p + o_c_uiT);
            int* cnt_vv  = (int*)(p + o_c_vv);
            int* bsum    = (int*)(p + o_bsum);
            int2* e_ui   = (int2*)(p + o_e_ui2);
            int2* e_uiT  = (int2*)(p + o_e_uiT2);
            int2* e_uu   = (int2*)(p + o_e_uu2);
            int2* e_vv   = (int2*)(p + o_e_vv2);

            const int nbU2 = (U + SCAN_CHUNK - 1) / SCAN_CHUNK;
            const int nbI2 = (I + SCAN_CHUNK - 1) / SCAN_CHUNK;
            size_t cnt_span = (size_t)((p + o_c_vv + (size_t)I * 4) - (char*)cnt_ui);

            hipMemsetAsync(cnt_ui, 0, cnt_span, stream);
            hist4<<<nblk((long)nnz_ui * 2 + nnz_uu + nnz_vv, 4096), BLOCK, 0, stream>>>(
                ui_rows, nnz_ui, cnt_ui, uu_rows, nnz_uu, cnt_uu,
                ui_cols, nnz_ui, cnt_uiT, vv_rows, nnz_vv, cnt_vv);
            block_sums4<<<2 * nbU2 + 2 * nbI2, 256, 0, stream>>>(
                cnt_ui, U, nbU2, cnt_uu, U, nbU2, cnt_uiT, I, nbI2, cnt_vv, I, nbI2, bsum);
            scan_bsums4<<<4, NBMAX, 0, stream>>>(
                bsum, nbU2, nbU2, nbI2, nbI2, rp_ui, U, rp_uu, U, rp_uiT, I, rp_vv, I);
            scan_chunks4<<<2 * nbU2 + 2 * nbI2, 256, 0, stream>>>(
                cnt_ui, U, nbU2, rp_ui, cnt_uu, U, nbU2, rp_uu,
                cnt_uiT, I, nbI2, rp_uiT, cnt_vv, I, nbI2, rp_vv, bsum);
            hipMemsetAsync(cnt_ui, 0, cnt_span, stream);
            scatter_dual<<<nblk(nnz_ui, 4096), BLOCK, 0, stream>>>(
                ui_rows, ui_cols, ui_vals, rp_ui, cnt_ui, e_ui, rp_uiT, cnt_uiT, e_uiT, nnz_ui);
            scatter_dual<<<nblk(nnz_uu, 4096), BLOCK, 0, stream>>>(
                uu_rows, uu_cols, uu_vals, rp_uu, cnt_uu, e_uu, nullptr, nullptr, nullptr, nnz_uu);
            scatter_dual<<<nblk(nnz_vv, 4096), BLOCK, 0, stream>>>(
                vv_rows, vv_cols, vv_vals, rp_vv, cnt_vv, e_vv, nullptr, nullptr, nullptr, nnz_vv);

            hipMemsetAsync(uacc, 0, (size_t)((p + o_iacc + (size_t)batch * DDIM * 4) - (char*)uacc), stream);
            gather_add<<<gb, BLOCK, 0, stream>>>(uacc, user_emb, users, batch);
            gather_add<<<gb, BLOCK, 0, stream>>>(iacc, item_emb, items, batch);

            first_comb4<<<nblk(UD / 4, 4096), BLOCK, 0, stream>>>(
                (float4*)uA, (const float4*)user_emb, du, UD / 4);
            first_comb4<<<nblk(ID / 4, 4096), BLOCK, 0, stream>>>(
                (float4*)iA, (const float4*)item_emb, dv, ID / 4);

            float* ucur = uA; float* unext = uB;
            float* icur = iA; float* inext = iB;
            int ub = (int)((UD + BLOCK - 1) / BLOCK);
            int ib = (int)((ID + BLOCK - 1) / BLOCK);

            for (int layer = 0; layer < 3; ++layer) {
                if (layer > 0) {
                    add_scaled4<<<nblk(UD / 4, 4096), BLOCK, 0, stream>>>(
                        (float4*)ucur, (const float4*)user_emb, du, UD / 4);
                    add_scaled4<<<nblk(ID / 4, 4096), BLOCK, 0, stream>>>(
                        (float4*)icur, (const float4*)item_emb, dv, ID / 4);
                }
                pull2csr<<<ub, BLOCK, 0, stream>>>(rp_ui, e_ui, icur, rp_uu, e_uu, ucur,
                                                   unext, nullptr, nullptr, nullptr, U);
                gather_add<<<gb, BLOCK, 0, stream>>>(uacc, unext, users, batch);
                if (layer < 2) {
                    pull2csr<<<ib, BLOCK, 0, stream>>>(rp_uiT, e_uiT, unext, rp_vv, e_vv, icur,
                                                       inext, nullptr, nullptr, nullptr, I);
                    gather_add<<<gb, BLOCK, 0, stream>>>(iacc, inext, items, batch);
                } else {
                    pull2csr_rows<<<gb, BLOCK, 0, stream>>>(rp_uiT, e_uiT, unext, rp_vv, e_vv, icur,
                                                            items, iacc, batch);
                }
                float* tt;
                tt = ucur; ucur = unext; unext = tt;
                tt = icur; icur = inext; inext = tt;
            }
            final_gamma<<<gb, BLOCK, 0, stream>>>(uacc, iacc, gamma, batch);
            return;
        }
    }

    // ---- tier 3: push-atomic fallback ----
    {
        float* uA = uRaw; float* uB = uAugA;
        float* iA = iAugA; float* iB = (float*)(p + base_end);   // needs ID*4 beyond base

        hipMemsetAsync(uacc, 0, (size_t)batch * DDIM * sizeof(float) * 2, stream);
        gather_add<<<gb, BLOCK, 0, stream>>>(uacc, user_emb, users, batch);
        gather_add<<<gb, BLOCK, 0, stream>>>(iacc, item_emb, items, batch);

        first_comb4<<<nblk(UD / 4, 4096), BLOCK, 0, stream>>>(
            (float4*)uA, (const float4*)user_emb, du, UD / 4);
        first_comb4<<<nblk(ID / 4, 4096), BLOCK, 0, stream>>>(
            (float4*)iA, (const float4*)item_emb, dv, ID / 4);

        float* ucur = uA; float* unext = uB;
        float* icur = iA; float* inext = iB;

        for (int layer = 0; layer < 3; ++layer) {
            if (layer > 0) {
                add_scaled4<<<nblk(UD / 4, 4096), BLOCK, 0, stream>>>(
                    (float4*)ucur, (const float4*)user_emb, du, UD / 4);
                add_scaled4<<<nblk(ID / 4, 4096), BLOCK, 0, stream>>>(
                    (float4*)icur, (const float4*)item_emb, dv, ID / 4);
            }
            hipMemsetAsync(unext, 0, UD * sizeof(float), stream);
            spmm_push<<<nblk((long)nnz_ui << 6, 16384), BLOCK, 0, stream>>>(
                ui_rows, ui_cols, ui_vals, icur, unext, nnz_ui);
            spmm_push<<<nblk((long)nnz_uu << 6, 16384), BLOCK, 0, stream>>>(
                uu_rows, uu_cols, uu_vals, ucur, unext, nnz_uu);
            hipMemsetAsync(inext, 0, ID * sizeof(float), stream);
            spmm_push<<<nblk((long)nnz_vv << 6, 16384), BLOCK, 0, stream>>>(
                vv_rows, vv_cols, vv_vals, icur, inext, nnz_vv);
            spmm_push<<<nblk((long)nnz_ui << 6, 16384), BLOCK, 0, stream>>>(
                ui_cols, ui_rows, ui_vals, unext, inext, nnz_ui);
            gather_add<<<gb, BLOCK, 0, stream>>>(uacc, unext, users, batch);
            gather_add<<<gb, BLOCK, 0, stream>>>(iacc, inext, items, batch);
            float* tt;
            tt = ucur; ucur = unext; unext = tt;
            tt = icur; icur = inext; inext = tt;
        }
        final_gamma<<<gb, BLOCK, 0, stream>>>(uacc, iacc, gamma, batch);
    }
}